// Round 7
// baseline (85.539 us; speedup 1.0000x reference)
//
#include <hip/hip_runtime.h>
#include <math.h>

#define NDIM 128
#define NHID 512
#define NEXPERT 64
#define NTOK 1024
#define NPAIR (NTOK * 2)

typedef __attribute__((ext_vector_type(8))) short short8_t;
typedef __attribute__((ext_vector_type(4))) float f32x4;

__device__ __forceinline__ float gelu_f(float v) {
    return 0.5f * v * (1.0f + erff(v * 0.7071067811865476f));
}

// f32 -> bf16 RNE
__device__ __forceinline__ unsigned short f2bf(float f) {
    union { float f; unsigned u; } v; v.f = f;
    unsigned r = v.u + 0x7FFFu + ((v.u >> 16) & 1u);
    return (unsigned short)(r >> 16);
}
__device__ __forceinline__ float bf2f(unsigned short h) {
    union { unsigned u; float f; } v; v.u = ((unsigned)h) << 16;
    return v.f;
}

// ---------------- gating: split-bf16 MFMA GEMM ----------------
// C = gelu(A[1024][K] @ B[K][512] + bias), f32-class accuracy via 3-term
// bf16 split (hh, mh, hm, lh, hl, mm -> dropped terms ~2^-24 relative).
// tile 32m x 64n, 256 threads (4 waves: wave w -> m-tile w&1, n-pair w>>1).
// MFMA conventions identical to the R6-verified expert kernels:
//   frag = row[ks*32 + (lane>>4)*8 + 0..7]; C[A-row=(lane>>4)*4+r][B-row=lane&15]
__global__ __launch_bounds__(256) void gemmsp_kernel(
        const float* __restrict__ A, const float* __restrict__ B,
        const float* __restrict__ bias, float* __restrict__ C, int K) {
    __shared__ short Ah[3][32][72];  // [lvl][m][k], row 144B (16B-aligned)
    __shared__ short Bt[3][64][72];  // [lvl][n][k] (B transposed)
    const int j = threadIdx.x;
    const int m0 = blockIdx.x * 32, n0 = blockIdx.y * 64;
    const int w = j >> 6, lane = j & 63;
    const int mt = w & 1, npair = w >> 1;
    const int lrow = lane & 15, lseg = lane >> 4;
    f32x4 acc[2];
    acc[0] = (f32x4){0.f, 0.f, 0.f, 0.f};
    acc[1] = (f32x4){0.f, 0.f, 0.f, 0.f};

    for (int kc = 0; kc < K; kc += 64) {
        __syncthreads();
        // stage A chunk: 32 x 64 f32 = 512 float4
#pragma unroll
        for (int q = 0; q < 2; ++q) {
            const int idx = j + 256 * q;
            const int row = idx >> 4, c4 = idx & 15;
            float4 v = *(const float4*)(A + (size_t)(m0 + row) * K + kc + c4 * 4);
#pragma unroll
            for (int i = 0; i < 4; ++i) {
                const float f = (&v.x)[i];
                const unsigned short h = f2bf(f);
                const float r1 = f - bf2f(h);
                const unsigned short m = f2bf(r1);
                const unsigned short l = f2bf(r1 - bf2f(m));
                Ah[0][row][c4 * 4 + i] = h;
                Ah[1][row][c4 * 4 + i] = m;
                Ah[2][row][c4 * 4 + i] = l;
            }
        }
        // stage B chunk transposed: 64 x 64 f32 = 1024 float4
#pragma unroll
        for (int q = 0; q < 4; ++q) {
            const int idx = j + 256 * q;
            const int kr = idx >> 4, c4 = idx & 15;
            float4 v = *(const float4*)(B + (size_t)(kc + kr) * NHID + n0 + c4 * 4);
#pragma unroll
            for (int i = 0; i < 4; ++i) {
                const float f = (&v.x)[i];
                const unsigned short h = f2bf(f);
                const float r1 = f - bf2f(h);
                const unsigned short m = f2bf(r1);
                const unsigned short l = f2bf(r1 - bf2f(m));
                const int n = c4 * 4 + i;
                Bt[0][n][kr] = h;
                Bt[1][n][kr] = m;
                Bt[2][n][kr] = l;
            }
        }
        __syncthreads();
#pragma unroll
        for (int ks = 0; ks < 2; ++ks) {
            const int ko = ks * 32 + lseg * 8;
            short8_t ah = *(short8_t*)&Ah[0][mt * 16 + lrow][ko];
            short8_t am = *(short8_t*)&Ah[1][mt * 16 + lrow][ko];
            short8_t al = *(short8_t*)&Ah[2][mt * 16 + lrow][ko];
#pragma unroll
            for (int nt = 0; nt < 2; ++nt) {
                const int nr = (npair * 2 + nt) * 16 + lrow;
                short8_t bh = *(short8_t*)&Bt[0][nr][ko];
                short8_t bm = *(short8_t*)&Bt[1][nr][ko];
                short8_t bl = *(short8_t*)&Bt[2][nr][ko];
                acc[nt] = __builtin_amdgcn_mfma_f32_16x16x32_bf16(ah, bh, acc[nt], 0, 0, 0);
                acc[nt] = __builtin_amdgcn_mfma_f32_16x16x32_bf16(am, bh, acc[nt], 0, 0, 0);
                acc[nt] = __builtin_amdgcn_mfma_f32_16x16x32_bf16(ah, bm, acc[nt], 0, 0, 0);
                acc[nt] = __builtin_amdgcn_mfma_f32_16x16x32_bf16(al, bh, acc[nt], 0, 0, 0);
                acc[nt] = __builtin_amdgcn_mfma_f32_16x16x32_bf16(ah, bl, acc[nt], 0, 0, 0);
                acc[nt] = __builtin_amdgcn_mfma_f32_16x16x32_bf16(am, bm, acc[nt], 0, 0, 0);
            }
        }
    }
#pragma unroll
    for (int nt = 0; nt < 2; ++nt) {
        const int col = n0 + (npair * 2 + nt) * 16 + lrow;
        const float bb = bias[col];
#pragma unroll
        for (int r = 0; r < 4; ++r) {
            const int row = m0 + mt * 16 + lseg * 4 + r;
            C[(size_t)row * NHID + col] = gelu_f(acc[nt][r] + bb);
        }
    }
}

// gate3: logits = h2 @ gw3 + gb3 (LDS-staged); sigmoid; top-2 (ties -> lower
// index); normalize. 64 blocks x 16 tokens; lane = expert.
__global__ __launch_bounds__(256) void gate3_top2_kernel(
        const float* __restrict__ h2, const float* __restrict__ gw3,
        const float* __restrict__ gb3, int* __restrict__ eidx,
        float* __restrict__ wval) {
    __shared__ float hs[16][132];
    __shared__ float gs[128][72];
    const int j = threadIdx.x;
    const int t0 = blockIdx.x * 16;
    const int lane = j & 63;
    const int w = j >> 6;  // wave -> tokens w*4 .. w*4+3
    float acc[4] = {0.f, 0.f, 0.f, 0.f};
    for (int k0 = 0; k0 < NHID; k0 += 128) {
        __syncthreads();
        for (int idx = j; idx < 512; idx += 256) {  // 16 tok x 32 f4
            const int tok = idx >> 5, c4 = idx & 31;
            *(float4*)&hs[tok][c4 * 4] =
                *(const float4*)(h2 + (size_t)(t0 + tok) * NHID + k0 + c4 * 4);
        }
        for (int idx = j; idx < 2048; idx += 256) {  // 128 kk x 16 f4
            const int kk = idx >> 4, c4 = idx & 15;
            *(float4*)&gs[kk][c4 * 4] =
                *(const float4*)(gw3 + (size_t)(k0 + kk) * NEXPERT + c4 * 4);
        }
        __syncthreads();
        for (int kk = 0; kk < 128; ++kk) {
            const float g = gs[kk][lane];
#pragma unroll
            for (int i = 0; i < 4; ++i) acc[i] += hs[w * 4 + i][kk] * g;
        }
    }
    const float bias = gb3[lane];
#pragma unroll
    for (int i = 0; i < 4; ++i) {
        const int t = t0 + w * 4 + i;
        float s = 1.f / (1.f + expf(-(acc[i] + bias)));
        float v = s; int ix = lane;
#pragma unroll
        for (int off = 32; off >= 1; off >>= 1) {
            float ov = __shfl_xor(v, off);
            int oi = __shfl_xor(ix, off);
            if (ov > v || (ov == v && oi < ix)) { v = ov; ix = oi; }
        }
        const float v0 = v; const int i0 = ix;
        float v2 = (lane == i0) ? -1.f : s; int ix2 = lane;
#pragma unroll
        for (int off = 32; off >= 1; off >>= 1) {
            float ov = __shfl_xor(v2, off);
            int oi = __shfl_xor(ix2, off);
            if (ov > v2 || (ov == v2 && oi < ix2)) { v2 = ov; ix2 = oi; }
        }
        if (lane == 0) {
            float inv = 1.f / (v0 + v2);
            eidx[t * 2] = i0;  eidx[t * 2 + 1] = ix2;
            wval[t * 2] = v0 * inv;  wval[t * 2 + 1] = v2 * inv;
        }
    }
}

// deterministic per-expert lists via block scan (index order)
__global__ __launch_bounds__(256) void build_lists_kernel(
        const int* __restrict__ eidx, int* __restrict__ elist,
        int* __restrict__ ecnt) {
    const int e = blockIdx.x;
    const int j = threadIdx.x;
    __shared__ int cnts[256];
    int my[8];
    int mc = 0;
#pragma unroll
    for (int q = 0; q < 8; ++q) {
        int i = j * 8 + q;
        if (eidx[i] == e) my[mc++] = i;
    }
    cnts[j] = mc;
    __syncthreads();
    for (int off = 1; off < 256; off <<= 1) {
        int other = (j >= off) ? cnts[j - off] : 0;
        __syncthreads();
        cnts[j] += other;
        __syncthreads();
    }
    const int base = cnts[j] - mc;
    for (int q = 0; q < mc; ++q) elist[e * NPAIR + base + q] = my[q];
    if (j == 255) ecnt[e] = cnts[255];
}

// ---------------- experts (bf16 MFMA, verified R6) ----------------
#define L1_ROWSH 136  // shorts per row (272 B)

// expert layer1: grid (64 e, 8 f-chunks of 64). tile 32 tok x 64 f, K=128.
__global__ __launch_bounds__(256) void expert_l1_kernel(
        const float* __restrict__ x, const float* __restrict__ W1,
        const float* __restrict__ B1, const int* __restrict__ elist,
        const int* __restrict__ ecnt, unsigned short* __restrict__ tbuf) {
    __shared__ short As[32 * L1_ROWSH];
    __shared__ short Bs[64 * L1_ROWSH];
    __shared__ int prs[32];
    const int e = blockIdx.x;
    const int f0 = blockIdx.y * 64;
    const int n = ecnt[e];
    const int* le = elist + e * NPAIR;
    const float* W1e = W1 + (size_t)e * NHID * NDIM;
    const int j = threadIdx.x;
    const int lane = j & 63;
    const int w = j >> 6;
    char* Asc = (char*)As;
    char* Bsc = (char*)Bs;
    for (int idx = j; idx < 2048; idx += 256) {
        const int f = idx >> 5, c4 = idx & 31;
        float4 v = *(const float4*)(W1e + (size_t)(f0 + f) * NDIM + c4 * 4);
        short4 s; s.x = f2bf(v.x); s.y = f2bf(v.y); s.z = f2bf(v.z); s.w = f2bf(v.w);
        *(short4*)(Bsc + f * 272 + c4 * 8) = s;
    }
    const float bbias = B1[e * NHID + f0 + w * 16 + (lane & 15)];
    for (int bt = 0; bt * 32 < n; ++bt) {
        const int nb = min(32, n - bt * 32);
        __syncthreads();
        if (j < 32) prs[j] = (j < nb) ? le[bt * 32 + j] : -1;
        __syncthreads();
        for (int idx = j; idx < 1024; idx += 256) {
            const int tok = idx >> 5, c4 = idx & 31;
            const int pr = prs[tok];
            float4 v = make_float4(0.f, 0.f, 0.f, 0.f);
            if (pr >= 0) v = ((const float4*)x)[(size_t)(pr >> 1) * 32 + c4];
            short4 s; s.x = f2bf(v.x); s.y = f2bf(v.y); s.z = f2bf(v.z); s.w = f2bf(v.w);
            *(short4*)(Asc + tok * 272 + c4 * 8) = s;
        }
        __syncthreads();
        f32x4 acc[2];
        acc[0] = (f32x4){0.f, 0.f, 0.f, 0.f};
        acc[1] = (f32x4){0.f, 0.f, 0.f, 0.f};
        const int acol = ((lane >> 4) << 4);
        const int brow = w * 16 + (lane & 15);
#pragma unroll
        for (int ks = 0; ks < 4; ++ks) {
            short8_t b = *(short8_t*)(Bsc + brow * 272 + ks * 64 + acol);
#pragma unroll
            for (int mt = 0; mt < 2; ++mt) {
                short8_t a = *(short8_t*)(Asc + (mt * 16 + (lane & 15)) * 272 + ks * 64 + acol);
                acc[mt] = __builtin_amdgcn_mfma_f32_16x16x32_bf16(a, b, acc[mt], 0, 0, 0);
            }
        }
        const int fcol = f0 + w * 16 + (lane & 15);
#pragma unroll
        for (int mt = 0; mt < 2; ++mt) {
#pragma unroll
            for (int r = 0; r < 4; ++r) {
                const int tok = mt * 16 + ((lane >> 4) << 2) + r;
                const int pr = prs[tok];
                if (pr >= 0)
                    tbuf[(size_t)pr * NHID + fcol] = f2bf(gelu_f(acc[mt][r] + bbias));
            }
        }
    }
}

// expert layer2: grid (64 e, 2 d-chunks of 64, 4 k-splits of 128).
__global__ __launch_bounds__(256) void expert_l2_kernel(
        const float* __restrict__ W2, const int* __restrict__ elist,
        const int* __restrict__ ecnt, const unsigned short* __restrict__ tbuf,
        float* __restrict__ pbuf) {
    __shared__ short As[32 * L1_ROWSH];
    __shared__ short Bs[64 * L1_ROWSH];
    __shared__ int prs[32];
    const int e = blockIdx.x;
    const int d0 = blockIdx.y * 64;
    const int kz = blockIdx.z;
    const int k0 = kz * 128;
    const int n = ecnt[e];
    const int* le = elist + e * NPAIR;
    const float* W2e = W2 + (size_t)e * NDIM * NHID;
    const int j = threadIdx.x;
    const int lane = j & 63;
    const int w = j >> 6;
    char* Asc = (char*)As;
    char* Bsc = (char*)Bs;
    for (int idx = j; idx < 2048; idx += 256) {
        const int d = idx >> 5, c4 = idx & 31;
        float4 v = *(const float4*)(W2e + (size_t)(d0 + d) * NHID + k0 + c4 * 4);
        short4 s; s.x = f2bf(v.x); s.y = f2bf(v.y); s.z = f2bf(v.z); s.w = f2bf(v.w);
        *(short4*)(Bsc + d * 272 + c4 * 8) = s;
    }
    float* pz = pbuf + (size_t)kz * NPAIR * NDIM;
    for (int bt = 0; bt * 32 < n; ++bt) {
        const int nb = min(32, n - bt * 32);
        __syncthreads();
        if (j < 32) prs[j] = (j < nb) ? le[bt * 32 + j] : -1;
        __syncthreads();
        for (int idx = j; idx < 512; idx += 256) {
            const int tok = idx >> 4, c8 = idx & 15;
            const int pr = prs[tok];
            short8_t v = (short8_t)(short)0;
            if (pr >= 0) v = *(const short8_t*)(tbuf + (size_t)pr * NHID + k0 + c8 * 8);
            *(short8_t*)(Asc + tok * 272 + c8 * 16) = v;
        }
        __syncthreads();
        f32x4 acc[2];
        acc[0] = (f32x4){0.f, 0.f, 0.f, 0.f};
        acc[1] = (f32x4){0.f, 0.f, 0.f, 0.f};
        const int acol = ((lane >> 4) << 4);
        const int brow = w * 16 + (lane & 15);
#pragma unroll
        for (int ks = 0; ks < 4; ++ks) {
            short8_t b = *(short8_t*)(Bsc + brow * 272 + ks * 64 + acol);
#pragma unroll
            for (int mt = 0; mt < 2; ++mt) {
                short8_t a = *(short8_t*)(Asc + (mt * 16 + (lane & 15)) * 272 + ks * 64 + acol);
                acc[mt] = __builtin_amdgcn_mfma_f32_16x16x32_bf16(a, b, acc[mt], 0, 0, 0);
            }
        }
        const int dcol = d0 + w * 16 + (lane & 15);
#pragma unroll
        for (int mt = 0; mt < 2; ++mt) {
#pragma unroll
            for (int r = 0; r < 4; ++r) {
                const int tok = mt * 16 + ((lane >> 4) << 2) + r;
                const int pr = prs[tok];
                if (pr >= 0) pz[(size_t)pr * NDIM + dcol] = acc[mt][r];
            }
        }
    }
}

// final: out[t,d] = sum_k wval[t,k] * gelu(sum_kz pbuf[kz] + B2[e,d])
__global__ __launch_bounds__(256) void combine_kernel(
        const float* __restrict__ pbuf, const float* __restrict__ wval,
        const int* __restrict__ eidx, const float* __restrict__ B2,
        float* __restrict__ out) {
    const int i = blockIdx.x * 256 + threadIdx.x;
    const int t = i >> 7, d = i & (NDIM - 1);
    const int KS = NPAIR * NDIM;
    float y[2];
#pragma unroll
    for (int k = 0; k < 2; ++k) {
        const int p = t * 2 + k;
        float s = pbuf[p * NDIM + d] + pbuf[KS + p * NDIM + d]
                + pbuf[2 * KS + p * NDIM + d] + pbuf[3 * KS + p * NDIM + d]
                + B2[eidx[p] * NDIM + d];
        y[k] = gelu_f(s);
    }
    out[i] = wval[t * 2] * y[0] + wval[t * 2 + 1] * y[1];
}

extern "C" void kernel_launch(void* const* d_in, const int* in_sizes, int n_in,
                              void* d_out, int out_size, void* d_ws, size_t ws_size,
                              hipStream_t stream) {
    const float* x   = (const float*)d_in[0];
    const float* gw1 = (const float*)d_in[1];
    const float* gb1 = (const float*)d_in[2];
    const float* gw2 = (const float*)d_in[3];
    const float* gb2 = (const float*)d_in[4];
    const float* gw3 = (const float*)d_in[5];
    const float* gb3 = (const float*)d_in[6];
    const float* W1  = (const float*)d_in[7];
    const float* B1  = (const float*)d_in[8];
    const float* W2  = (const float*)d_in[9];
    const float* B2  = (const float*)d_in[10];
    float* out = (float*)d_out;

    char* ws = (char*)d_ws;
    // h1 [0,2MB) | h2 [2,4MB) | tbuf(bf16,2MB) aliases h1 after gate3 |
    // pbuf [4,8MB) 4x1MB | control at 8MB+
    float*          h1   = (float*)(ws);
    float*          h2   = (float*)(ws + (2ull << 20));
    unsigned short* tbuf = (unsigned short*)(ws);
    float*          pbuf = (float*)(ws + (4ull << 20));
    int*   eidx  = (int*)  (ws + (8ull << 20));
    float* wval  = (float*)(ws + (8ull << 20) + 8192);
    int*   elist = (int*)  (ws + (8ull << 20) + 16384);
    int*   ecnt  = (int*)  (ws + (8ull << 20) + 16384 + NEXPERT * NPAIR * 4);

    gemmsp_kernel<<<dim3(32, 8), 256, 0, stream>>>(x, gw1, gb1, h1, NDIM);
    gemmsp_kernel<<<dim3(32, 8), 256, 0, stream>>>(h1, gw2, gb2, h2, NHID);
    gate3_top2_kernel<<<dim3(NTOK / 16), 256, 0, stream>>>(h2, gw3, gb3, eidx, wval);
    build_lists_kernel<<<dim3(NEXPERT), 256, 0, stream>>>(eidx, elist, ecnt);
    expert_l1_kernel<<<dim3(NEXPERT, 8), 256, 0, stream>>>(x, W1, B1, elist, ecnt, tbuf);
    expert_l2_kernel<<<dim3(NEXPERT, 2, 4), 256, 0, stream>>>(W2, elist, ecnt, tbuf, pbuf);
    combine_kernel<<<dim3(NTOK * NDIM / 256), 256, 0, stream>>>(pbuf, wval, eidx, B2, out);
}

// Round 8
// 81.772 us; speedup vs baseline: 1.0461x; 1.0461x over previous
//
#include <hip/hip_runtime.h>
#include <math.h>

#define NDIM 128
#define NHID 512
#define NEXPERT 64
#define NTOK 1024
#define NPAIR (NTOK * 2)

typedef __attribute__((ext_vector_type(8))) short short8_t;
typedef __attribute__((ext_vector_type(4))) float f32x4;

__device__ __forceinline__ float gelu_f(float v) {
    return 0.5f * v * (1.0f + erff(v * 0.7071067811865476f));
}

// f32 -> bf16 RNE
__device__ __forceinline__ unsigned short f2bf(float f) {
    union { float f; unsigned u; } v; v.f = f;
    unsigned r = v.u + 0x7FFFu + ((v.u >> 16) & 1u);
    return (unsigned short)(r >> 16);
}
__device__ __forceinline__ float bf2f(unsigned short h) {
    union { unsigned u; float f; } v; v.u = ((unsigned)h) << 16;
    return v.f;
}

// ---------------- decomp: gw1/gw2 -> 3 bf16 planes, transposed to [n][k] ----
// grid 80 blocks: b<16 -> gw1 (K=128), else gw2 (K=512). 64x64 tiles.
__global__ __launch_bounds__(256) void decomp_kernel(
        const float* __restrict__ gw1, const float* __restrict__ gw2,
        unsigned short* __restrict__ G1h, unsigned short* __restrict__ G1m,
        unsigned short* __restrict__ G1l, unsigned short* __restrict__ G2h,
        unsigned short* __restrict__ G2m, unsigned short* __restrict__ G2l) {
    __shared__ float T[64][65];
    const int b = blockIdx.x;
    const int j = threadIdx.x;
    const float* src;
    unsigned short *Dh, *Dm, *Dl;
    int k0, n0, Kd;
    if (b < 16) {
        src = gw1; Dh = G1h; Dm = G1m; Dl = G1l;
        k0 = (b >> 3) * 64; n0 = (b & 7) * 64; Kd = 128;
    } else {
        const int bb = b - 16;
        src = gw2; Dh = G2h; Dm = G2m; Dl = G2l;
        k0 = (bb >> 3) * 64; n0 = (bb & 7) * 64; Kd = 512;
    }
#pragma unroll
    for (int q = 0; q < 4; ++q) {
        const int idx = j + 256 * q;
        const int kr = idx >> 4, c4 = idx & 15;
        float4 v = *(const float4*)(src + (size_t)(k0 + kr) * NHID + n0 + c4 * 4);
        T[kr][c4 * 4 + 0] = v.x; T[kr][c4 * 4 + 1] = v.y;
        T[kr][c4 * 4 + 2] = v.z; T[kr][c4 * 4 + 3] = v.w;
    }
    __syncthreads();
#pragma unroll
    for (int q = 0; q < 4; ++q) {
        const int idx = j + 256 * q;
        const int n = idx >> 4, k4 = idx & 15;
        short4 sh, sm, sl;
#pragma unroll
        for (int qq = 0; qq < 4; ++qq) {
            const float f = T[k4 * 4 + qq][n];
            const unsigned short h = f2bf(f);
            const float r1 = f - bf2f(h);
            const unsigned short m = f2bf(r1);
            const unsigned short l = f2bf(r1 - bf2f(m));
            (&sh.x)[qq] = (short)h; (&sm.x)[qq] = (short)m; (&sl.x)[qq] = (short)l;
        }
        const size_t o = (size_t)(n0 + n) * Kd + k0 + k4 * 4;
        *(short4*)(Dh + o) = sh;
        *(short4*)(Dm + o) = sm;
        *(short4*)(Dl + o) = sl;
    }
}

// ---------------- gating GEMM: 3-plane split-bf16 MFMA ----------------
// C = gelu(A[1024][K] @ B[K][512] + bias). B given as 3 planes [n][k].
// amode 0: A = f32 (decompose in staging). amode 1: A = 3 bf16 planes [m][k].
// epi 0: write 3 bf16 planes. epi 1: write f32.
// MFMA mapping identical to R6-verified experts; product order = R7 (passed).
__global__ __launch_bounds__(256) void gatemm_kernel(
        const float* __restrict__ Af,
        const unsigned short* __restrict__ Ahp, const unsigned short* __restrict__ Amp,
        const unsigned short* __restrict__ Alp,
        const unsigned short* __restrict__ Bhp, const unsigned short* __restrict__ Bmp,
        const unsigned short* __restrict__ Blp,
        const float* __restrict__ bias, float* __restrict__ Cf,
        unsigned short* __restrict__ Chp, unsigned short* __restrict__ Cmp,
        unsigned short* __restrict__ Clp,
        int K, int amode, int epi) {
    __shared__ short Ahs[3][32][72];
    __shared__ short Bss[3][64][72];
    const int j = threadIdx.x;
    const int m0 = blockIdx.x * 32, n0 = blockIdx.y * 64;
    const int w = j >> 6, lane = j & 63;
    const int mt = w & 1, npair = w >> 1;
    const int lrow = lane & 15, lseg = lane >> 4;
    f32x4 acc[2];
    acc[0] = (f32x4){0.f, 0.f, 0.f, 0.f};
    acc[1] = (f32x4){0.f, 0.f, 0.f, 0.f};

    for (int kc = 0; kc < K; kc += 64) {
        __syncthreads();
        if (amode == 0) {
            // A f32: 32 x 64 = 512 float4, 2/thread, decompose inline
#pragma unroll
            for (int q = 0; q < 2; ++q) {
                const int idx = j + 256 * q;
                const int row = idx >> 4, c4 = idx & 15;
                float4 v = *(const float4*)(Af + (size_t)(m0 + row) * K + kc + c4 * 4);
#pragma unroll
                for (int i = 0; i < 4; ++i) {
                    const float f = (&v.x)[i];
                    const unsigned short h = f2bf(f);
                    const float r1 = f - bf2f(h);
                    const unsigned short m = f2bf(r1);
                    const unsigned short l = f2bf(r1 - bf2f(m));
                    Ahs[0][row][c4 * 4 + i] = (short)h;
                    Ahs[1][row][c4 * 4 + i] = (short)m;
                    Ahs[2][row][c4 * 4 + i] = (short)l;
                }
            }
        } else {
            // A planes: 32 rows x 8 short8 = 256 per plane, 1/thread each
            const int row = j >> 3, c8 = j & 7;
            const size_t o = (size_t)(m0 + row) * K + kc + c8 * 8;
            *(short8_t*)&Ahs[0][row][c8 * 8] = *(const short8_t*)(Ahp + o);
            *(short8_t*)&Ahs[1][row][c8 * 8] = *(const short8_t*)(Amp + o);
            *(short8_t*)&Ahs[2][row][c8 * 8] = *(const short8_t*)(Alp + o);
        }
        // B planes: 64 rows x 8 short8 = 512 per plane, 2/thread each
#pragma unroll
        for (int q = 0; q < 2; ++q) {
            const int idx = j + 256 * q;
            const int nr = idx >> 3, c8 = idx & 7;
            const size_t o = (size_t)(n0 + nr) * K + kc + c8 * 8;
            *(short8_t*)&Bss[0][nr][c8 * 8] = *(const short8_t*)(Bhp + o);
            *(short8_t*)&Bss[1][nr][c8 * 8] = *(const short8_t*)(Bmp + o);
            *(short8_t*)&Bss[2][nr][c8 * 8] = *(const short8_t*)(Blp + o);
        }
        __syncthreads();
#pragma unroll
        for (int ks = 0; ks < 2; ++ks) {
            const int ko = ks * 32 + lseg * 8;
            short8_t ah = *(short8_t*)&Ahs[0][mt * 16 + lrow][ko];
            short8_t am = *(short8_t*)&Ahs[1][mt * 16 + lrow][ko];
            short8_t al = *(short8_t*)&Ahs[2][mt * 16 + lrow][ko];
#pragma unroll
            for (int nt = 0; nt < 2; ++nt) {
                const int nr = (npair * 2 + nt) * 16 + lrow;
                short8_t bh = *(short8_t*)&Bss[0][nr][ko];
                short8_t bm = *(short8_t*)&Bss[1][nr][ko];
                short8_t bl = *(short8_t*)&Bss[2][nr][ko];
                acc[nt] = __builtin_amdgcn_mfma_f32_16x16x32_bf16(ah, bh, acc[nt], 0, 0, 0);
                acc[nt] = __builtin_amdgcn_mfma_f32_16x16x32_bf16(am, bh, acc[nt], 0, 0, 0);
                acc[nt] = __builtin_amdgcn_mfma_f32_16x16x32_bf16(ah, bm, acc[nt], 0, 0, 0);
                acc[nt] = __builtin_amdgcn_mfma_f32_16x16x32_bf16(al, bh, acc[nt], 0, 0, 0);
                acc[nt] = __builtin_amdgcn_mfma_f32_16x16x32_bf16(ah, bl, acc[nt], 0, 0, 0);
                acc[nt] = __builtin_amdgcn_mfma_f32_16x16x32_bf16(am, bm, acc[nt], 0, 0, 0);
            }
        }
    }
#pragma unroll
    for (int nt = 0; nt < 2; ++nt) {
        const int col = n0 + (npair * 2 + nt) * 16 + lrow;
        const float bb = bias[col];
#pragma unroll
        for (int r = 0; r < 4; ++r) {
            const int row = m0 + mt * 16 + lseg * 4 + r;
            const float h = gelu_f(acc[nt][r] + bb);
            if (epi == 0) {
                const unsigned short hh = f2bf(h);
                const float r1 = h - bf2f(hh);
                const unsigned short hm = f2bf(r1);
                const unsigned short hl = f2bf(r1 - bf2f(hm));
                const size_t o = (size_t)row * NHID + col;
                Chp[o] = hh; Cmp[o] = hm; Clp[o] = hl;
            } else {
                Cf[(size_t)row * NHID + col] = h;
            }
        }
    }
}

// gate3: logits = h2 @ gw3 + gb3 (LDS-staged); sigmoid; top-2 (ties -> lower
// index); normalize. 64 blocks x 16 tokens; lane = expert.
__global__ __launch_bounds__(256) void gate3_top2_kernel(
        const float* __restrict__ h2, const float* __restrict__ gw3,
        const float* __restrict__ gb3, int* __restrict__ eidx,
        float* __restrict__ wval) {
    __shared__ float hs[16][132];
    __shared__ float gs[128][72];
    const int j = threadIdx.x;
    const int t0 = blockIdx.x * 16;
    const int lane = j & 63;
    const int w = j >> 6;  // wave -> tokens w*4 .. w*4+3
    float acc[4] = {0.f, 0.f, 0.f, 0.f};
    for (int k0 = 0; k0 < NHID; k0 += 128) {
        __syncthreads();
        for (int idx = j; idx < 512; idx += 256) {
            const int tok = idx >> 5, c4 = idx & 31;
            *(float4*)&hs[tok][c4 * 4] =
                *(const float4*)(h2 + (size_t)(t0 + tok) * NHID + k0 + c4 * 4);
        }
        for (int idx = j; idx < 2048; idx += 256) {
            const int kk = idx >> 4, c4 = idx & 15;
            *(float4*)&gs[kk][c4 * 4] =
                *(const float4*)(gw3 + (size_t)(k0 + kk) * NEXPERT + c4 * 4);
        }
        __syncthreads();
        for (int kk = 0; kk < 128; ++kk) {
            const float g = gs[kk][lane];
#pragma unroll
            for (int i = 0; i < 4; ++i) acc[i] += hs[w * 4 + i][kk] * g;
        }
    }
    const float bias = gb3[lane];
#pragma unroll
    for (int i = 0; i < 4; ++i) {
        const int t = t0 + w * 4 + i;
        float s = 1.f / (1.f + expf(-(acc[i] + bias)));
        float v = s; int ix = lane;
#pragma unroll
        for (int off = 32; off >= 1; off >>= 1) {
            float ov = __shfl_xor(v, off);
            int oi = __shfl_xor(ix, off);
            if (ov > v || (ov == v && oi < ix)) { v = ov; ix = oi; }
        }
        const float v0 = v; const int i0 = ix;
        float v2 = (lane == i0) ? -1.f : s; int ix2 = lane;
#pragma unroll
        for (int off = 32; off >= 1; off >>= 1) {
            float ov = __shfl_xor(v2, off);
            int oi = __shfl_xor(ix2, off);
            if (ov > v2 || (ov == v2 && oi < ix2)) { v2 = ov; ix2 = oi; }
        }
        if (lane == 0) {
            float inv = 1.f / (v0 + v2);
            eidx[t * 2] = i0;  eidx[t * 2 + 1] = ix2;
            wval[t * 2] = v0 * inv;  wval[t * 2 + 1] = v2 * inv;
        }
    }
}

// deterministic per-expert lists via block scan (index order)
__global__ __launch_bounds__(256) void build_lists_kernel(
        const int* __restrict__ eidx, int* __restrict__ elist,
        int* __restrict__ ecnt) {
    const int e = blockIdx.x;
    const int j = threadIdx.x;
    __shared__ int cnts[256];
    int my[8];
    int mc = 0;
#pragma unroll
    for (int q = 0; q < 8; ++q) {
        int i = j * 8 + q;
        if (eidx[i] == e) my[mc++] = i;
    }
    cnts[j] = mc;
    __syncthreads();
    for (int off = 1; off < 256; off <<= 1) {
        int other = (j >= off) ? cnts[j - off] : 0;
        __syncthreads();
        cnts[j] += other;
        __syncthreads();
    }
    const int base = cnts[j] - mc;
    for (int q = 0; q < mc; ++q) elist[e * NPAIR + base + q] = my[q];
    if (j == 255) ecnt[e] = cnts[255];
}

// ---------------- experts (bf16 MFMA, verified R6) ----------------
#define L1_ROWSH 136  // shorts per row (272 B)

__global__ __launch_bounds__(256) void expert_l1_kernel(
        const float* __restrict__ x, const float* __restrict__ W1,
        const float* __restrict__ B1, const int* __restrict__ elist,
        const int* __restrict__ ecnt, unsigned short* __restrict__ tbuf) {
    __shared__ short As[32 * L1_ROWSH];
    __shared__ short Bs[64 * L1_ROWSH];
    __shared__ int prs[32];
    const int e = blockIdx.x;
    const int f0 = blockIdx.y * 64;
    const int n = ecnt[e];
    const int* le = elist + e * NPAIR;
    const float* W1e = W1 + (size_t)e * NHID * NDIM;
    const int j = threadIdx.x;
    const int lane = j & 63;
    const int w = j >> 6;
    char* Asc = (char*)As;
    char* Bsc = (char*)Bs;
    for (int idx = j; idx < 2048; idx += 256) {
        const int f = idx >> 5, c4 = idx & 31;
        float4 v = *(const float4*)(W1e + (size_t)(f0 + f) * NDIM + c4 * 4);
        short4 s; s.x = f2bf(v.x); s.y = f2bf(v.y); s.z = f2bf(v.z); s.w = f2bf(v.w);
        *(short4*)(Bsc + f * 272 + c4 * 8) = s;
    }
    const float bbias = B1[e * NHID + f0 + w * 16 + (lane & 15)];
    for (int bt = 0; bt * 32 < n; ++bt) {
        const int nb = min(32, n - bt * 32);
        __syncthreads();
        if (j < 32) prs[j] = (j < nb) ? le[bt * 32 + j] : -1;
        __syncthreads();
        for (int idx = j; idx < 1024; idx += 256) {
            const int tok = idx >> 5, c4 = idx & 31;
            const int pr = prs[tok];
            float4 v = make_float4(0.f, 0.f, 0.f, 0.f);
            if (pr >= 0) v = ((const float4*)x)[(size_t)(pr >> 1) * 32 + c4];
            short4 s; s.x = f2bf(v.x); s.y = f2bf(v.y); s.z = f2bf(v.z); s.w = f2bf(v.w);
            *(short4*)(Asc + tok * 272 + c4 * 8) = s;
        }
        __syncthreads();
        f32x4 acc[2];
        acc[0] = (f32x4){0.f, 0.f, 0.f, 0.f};
        acc[1] = (f32x4){0.f, 0.f, 0.f, 0.f};
        const int acol = ((lane >> 4) << 4);
        const int brow = w * 16 + (lane & 15);
#pragma unroll
        for (int ks = 0; ks < 4; ++ks) {
            short8_t b = *(short8_t*)(Bsc + brow * 272 + ks * 64 + acol);
#pragma unroll
            for (int mt = 0; mt < 2; ++mt) {
                short8_t a = *(short8_t*)(Asc + (mt * 16 + (lane & 15)) * 272 + ks * 64 + acol);
                acc[mt] = __builtin_amdgcn_mfma_f32_16x16x32_bf16(a, b, acc[mt], 0, 0, 0);
            }
        }
        const int fcol = f0 + w * 16 + (lane & 15);
#pragma unroll
        for (int mt = 0; mt < 2; ++mt) {
#pragma unroll
            for (int r = 0; r < 4; ++r) {
                const int tok = mt * 16 + ((lane >> 4) << 2) + r;
                const int pr = prs[tok];
                if (pr >= 0)
                    tbuf[(size_t)pr * NHID + fcol] = f2bf(gelu_f(acc[mt][r] + bbias));
            }
        }
    }
}

__global__ __launch_bounds__(256) void expert_l2_kernel(
        const float* __restrict__ W2, const int* __restrict__ elist,
        const int* __restrict__ ecnt, const unsigned short* __restrict__ tbuf,
        float* __restrict__ pbuf) {
    __shared__ short As[32 * L1_ROWSH];
    __shared__ short Bs[64 * L1_ROWSH];
    __shared__ int prs[32];
    const int e = blockIdx.x;
    const int d0 = blockIdx.y * 64;
    const int kz = blockIdx.z;
    const int k0 = kz * 128;
    const int n = ecnt[e];
    const int* le = elist + e * NPAIR;
    const float* W2e = W2 + (size_t)e * NDIM * NHID;
    const int j = threadIdx.x;
    const int lane = j & 63;
    const int w = j >> 6;
    char* Asc = (char*)As;
    char* Bsc = (char*)Bs;
    for (int idx = j; idx < 2048; idx += 256) {
        const int d = idx >> 5, c4 = idx & 31;
        float4 v = *(const float4*)(W2e + (size_t)(d0 + d) * NHID + k0 + c4 * 4);
        short4 s; s.x = f2bf(v.x); s.y = f2bf(v.y); s.z = f2bf(v.z); s.w = f2bf(v.w);
        *(short4*)(Bsc + d * 272 + c4 * 8) = s;
    }
    float* pz = pbuf + (size_t)kz * NPAIR * NDIM;
    for (int bt = 0; bt * 32 < n; ++bt) {
        const int nb = min(32, n - bt * 32);
        __syncthreads();
        if (j < 32) prs[j] = (j < nb) ? le[bt * 32 + j] : -1;
        __syncthreads();
        for (int idx = j; idx < 512; idx += 256) {
            const int tok = idx >> 4, c8 = idx & 15;
            const int pr = prs[tok];
            short8_t v = (short8_t)(short)0;
            if (pr >= 0) v = *(const short8_t*)(tbuf + (size_t)pr * NHID + k0 + c8 * 8);
            *(short8_t*)(Asc + tok * 272 + c8 * 16) = v;
        }
        __syncthreads();
        f32x4 acc[2];
        acc[0] = (f32x4){0.f, 0.f, 0.f, 0.f};
        acc[1] = (f32x4){0.f, 0.f, 0.f, 0.f};
        const int acol = ((lane >> 4) << 4);
        const int brow = w * 16 + (lane & 15);
#pragma unroll
        for (int ks = 0; ks < 4; ++ks) {
            short8_t b = *(short8_t*)(Bsc + brow * 272 + ks * 64 + acol);
#pragma unroll
            for (int mt = 0; mt < 2; ++mt) {
                short8_t a = *(short8_t*)(Asc + (mt * 16 + (lane & 15)) * 272 + ks * 64 + acol);
                acc[mt] = __builtin_amdgcn_mfma_f32_16x16x32_bf16(a, b, acc[mt], 0, 0, 0);
            }
        }
        const int dcol = d0 + w * 16 + (lane & 15);
#pragma unroll
        for (int mt = 0; mt < 2; ++mt) {
#pragma unroll
            for (int r = 0; r < 4; ++r) {
                const int tok = mt * 16 + ((lane >> 4) << 2) + r;
                const int pr = prs[tok];
                if (pr >= 0) pz[(size_t)pr * NDIM + dcol] = acc[mt][r];
            }
        }
    }
}

// final: out[t,d] = sum_k wval[t,k] * gelu(sum_kz pbuf[kz] + B2[e,d])
__global__ __launch_bounds__(256) void combine_kernel(
        const float* __restrict__ pbuf, const float* __restrict__ wval,
        const int* __restrict__ eidx, const float* __restrict__ B2,
        float* __restrict__ out) {
    const int i = blockIdx.x * 256 + threadIdx.x;
    const int t = i >> 7, d = i & (NDIM - 1);
    const int KS = NPAIR * NDIM;
    float y[2];
#pragma unroll
    for (int k = 0; k < 2; ++k) {
        const int p = t * 2 + k;
        float s = pbuf[p * NDIM + d] + pbuf[KS + p * NDIM + d]
                + pbuf[2 * KS + p * NDIM + d] + pbuf[3 * KS + p * NDIM + d]
                + B2[eidx[p] * NDIM + d];
        y[k] = gelu_f(s);
    }
    out[i] = wval[t * 2] * y[0] + wval[t * 2 + 1] * y[1];
}

extern "C" void kernel_launch(void* const* d_in, const int* in_sizes, int n_in,
                              void* d_out, int out_size, void* d_ws, size_t ws_size,
                              hipStream_t stream) {
    const float* x   = (const float*)d_in[0];
    const float* gw1 = (const float*)d_in[1];
    const float* gb1 = (const float*)d_in[2];
    const float* gw2 = (const float*)d_in[3];
    const float* gb2 = (const float*)d_in[4];
    const float* gw3 = (const float*)d_in[5];
    const float* gb3 = (const float*)d_in[6];
    const float* W1  = (const float*)d_in[7];
    const float* B1  = (const float*)d_in[8];
    const float* W2  = (const float*)d_in[9];
    const float* B2  = (const float*)d_in[10];
    float* out = (float*)d_out;

    char* ws = (char*)d_ws;
    // G1 planes [0, 0.375MB) | G2 planes [0.5, 2MB) | H1 planes [2, 5MB) |
    // h2 [5, 7MB) | tbuf aliases [0, 2MB) (G dead after gate2) |
    // pbuf [7, 11MB) | control [11MB+)
    unsigned short* G1h = (unsigned short*)(ws);
    unsigned short* G1m = (unsigned short*)(ws + 131072);
    unsigned short* G1l = (unsigned short*)(ws + 262144);
    unsigned short* G2h = (unsigned short*)(ws + 524288);
    unsigned short* G2m = (unsigned short*)(ws + 1048576);
    unsigned short* G2l = (unsigned short*)(ws + 1572864);
    unsigned short* Hh  = (unsigned short*)(ws + (2ull << 20));
    unsigned short* Hm  = (unsigned short*)(ws + (3ull << 20));
    unsigned short* Hl  = (unsigned short*)(ws + (4ull << 20));
    float*          h2  = (float*)(ws + (5ull << 20));
    unsigned short* tbuf = (unsigned short*)(ws);
    float*          pbuf = (float*)(ws + (7ull << 20));
    int*   eidx  = (int*)  (ws + (11ull << 20));
    float* wval  = (float*)(ws + (11ull << 20) + 8192);
    int*   elist = (int*)  (ws + (11ull << 20) + 16384);
    int*   ecnt  = (int*)  (ws + (11ull << 20) + 16384 + NEXPERT * NPAIR * 4);

    decomp_kernel<<<dim3(80), 256, 0, stream>>>(gw1, gw2, G1h, G1m, G1l, G2h, G2m, G2l);
    gatemm_kernel<<<dim3(32, 8), 256, 0, stream>>>(
        x, nullptr, nullptr, nullptr, G1h, G1m, G1l, gb1,
        nullptr, Hh, Hm, Hl, NDIM, 0, 0);
    gatemm_kernel<<<dim3(32, 8), 256, 0, stream>>>(
        nullptr, Hh, Hm, Hl, G2h, G2m, G2l, gb2,
        h2, nullptr, nullptr, nullptr, NHID, 1, 1);
    gate3_top2_kernel<<<dim3(NTOK / 16), 256, 0, stream>>>(h2, gw3, gb3, eidx, wval);
    build_lists_kernel<<<dim3(NEXPERT), 256, 0, stream>>>(eidx, elist, ecnt);
    expert_l1_kernel<<<dim3(NEXPERT, 8), 256, 0, stream>>>(x, W1, B1, elist, ecnt, tbuf);
    expert_l2_kernel<<<dim3(NEXPERT, 2, 4), 256, 0, stream>>>(W2, elist, ecnt, tbuf, pbuf);
    combine_kernel<<<dim3(NTOK * NDIM / 256), 256, 0, stream>>>(pbuf, wval, eidx, B2, out);
}